// Round 14
// baseline (238.754 us; speedup 1.0000x reference)
//
#include <hip/hip_runtime.h>
#include <hip/hip_bf16.h>

typedef float f32x4 __attribute__((ext_vector_type(4)));
typedef float f32x2 __attribute__((ext_vector_type(2)));
typedef unsigned short u16x4 __attribute__((ext_vector_type(4)));
typedef unsigned short u16x8 __attribute__((ext_vector_type(8)));
typedef short bf16x8 __attribute__((ext_vector_type(8)));

#define HID 128
#define RT  4    // 32-row steps per gemm block (block covers 128 rows)
#define ELLW 32  // ELL slot width: max degree ~17 on Poisson(4) input, 32 is safe

__device__ __forceinline__ float b2f(unsigned short u) {
    return __uint_as_float(((unsigned int)u) << 16);
}
__device__ __forceinline__ unsigned short f2b(float f) {
    unsigned int u = __float_as_uint(f);
    unsigned int r = (u + 0x7FFFu + ((u >> 16) & 1u)) >> 16;   // RNE
    return (unsigned short)r;
}

// --- runtime dtype probes (uniform across all threads; deterministic) -------
__device__ __forceinline__ bool detect_f32(const unsigned short* xp) {
    int sane = 0;
#pragma unroll
    for (int i = 0; i < 16; ++i) {
        int ex = (xp[2 * i] >> 7) & 0xFF;
        sane += (ex >= 120 && ex <= 130);
    }
    return sane < 8;   // true => float inputs are fp32
}
__device__ __forceinline__ bool detect_i64(const int* ei) {
    return (ei[1] | ei[3] | ei[5] | ei[7]) == 0;
}
__device__ __forceinline__ float ldf(const unsigned short* p, long i, bool f32) {
    return f32 ? ((const float*)p)[i] : b2f(p[i]);
}
// 4 contiguous floats at index c0, from bf16 or f32 storage
__device__ __forceinline__ f32x4 ld4(const unsigned short* p, int c0, bool f32) {
    if (f32) return *(const f32x4*)((const float*)p + c0);
    u16x4 q = *(const u16x4*)(p + c0);
    return (f32x4){b2f(q[0]), b2f(q[1]), b2f(q[2]), b2f(q[3])};
}
__device__ __forceinline__ int ei_at(const int* ei, long idx, bool i64) {
    return i64 ? ei[2 * idx] : ei[idx];
}
__device__ __forceinline__ float lrelu(float a) {
    return a > 0.f ? a : 0.2f * a;
}

// ---------------------------------------------------------------------------
// FUSED with INTERLEAVED roles, R10/R12/R13-proven form: every 3rd block
// (bid%3==2) runs the ELL scatter (4 strided edges/thread, phase-split
// atomics-then-stores); the rest run gemm1 (R4 body + R12 param hoist +
// R13 packed f32x2 al stores — fused dispatch measured 59-62us).
// DO NOT change geometry: 1:1/half-size scatter blocks regressed (R11);
// appended blocks serialize (R7/R8).
// ---------------------------------------------------------------------------
__global__ __launch_bounds__(256) void gemm1_scat_k(
    const unsigned short* __restrict__ x,
    const unsigned short* __restrict__ w,
    const unsigned short* __restrict__ bias,
    const unsigned short* __restrict__ a1s,
    const unsigned short* __restrict__ a1d,
    unsigned short* __restrict__ hp,
    float* __restrict__ al_s, float* __restrict__ al_d, int n_rows,
    const int* __restrict__ ei, int E,
    int* __restrict__ cursor, int* __restrict__ csrc, int gb, int sb)
{
    const int bid = (int)blockIdx.x;
    const int sb3 = 3 * sb;
    if (bid < sb3 && (bid % 3) == 2) {
        // ---- ELL scatter: 4 independent strided edges, phase-split ----
        const bool i64 = detect_i64(ei);
        const int nth = sb * 256;
        const int idx = (bid / 3) * 256 + (int)threadIdx.x;
        int s[4], d[4], pos[4]; bool v[4];
#pragma unroll
        for (int k = 0; k < 4; ++k) {
            int e = idx + k * nth;
            v[k] = e < E;
            if (v[k]) {
                s[k] = ei_at(ei, e, i64);
                d[k] = ei_at(ei, (long)E + e, i64);
            }
        }
#pragma unroll
        for (int k = 0; k < 4; ++k)
            if (v[k]) pos[k] = atomicAdd(&cursor[d[k]], 1);
#pragma unroll
        for (int k = 0; k < 4; ++k)
            if (v[k]) csrc[(d[k] << 5) + pos[k]] = s[k];
        return;
    }
    const int gidx = (bid < sb3) ? (bid - (bid + 1) / 3) : (bid - sb);
    if (gidx >= gb) return;

    // ---- gemm phase (proven form; params hoisted out of tt loop) ----
    const bool f32m = detect_f32(x);
    const int wave  = threadIdx.x >> 6;
    const int lane  = threadIdx.x & 63;
    const int nhalf = wave & 1;   // which 64-col half
    const int rtile = wave >> 1;  // which 16-row subtile
    const int m     = lane & 15;
    const int quad  = lane >> 4;

    // W fragments: loaded once, reused across all RT tiles (A operand)
    bf16x8 wfrag[4][4];
#pragma unroll
    for (int ks = 0; ks < 4; ++ks)
#pragma unroll
        for (int nt = 0; nt < 4; ++nt) {
            int col = nhalf * 64 + nt * 16 + m;
            if (!f32m) {
                wfrag[ks][nt] = *(const bf16x8*)(w + (long)col * HID + ks * 32 + quad * 8);
            } else {
                const float* wf = (const float*)w;
#pragma unroll
                for (int j = 0; j < 8; ++j)
                    wfrag[ks][nt][j] = (short)f2b(wf[(long)col * HID + ks * 32 + quad * 8 + j]);
            }
        }

    // bias/attention params: tt-invariant — hoisted
    f32x4 bb[4], as4[4], ad4[4];
#pragma unroll
    for (int nt = 0; nt < 4; ++nt) {
        const int c0 = nhalf * 64 + nt * 16 + quad * 4;
        bb[nt]  = ld4(bias, c0, f32m);
        as4[nt] = ld4(a1s,  c0, f32m);
        ad4[nt] = ld4(a1d,  c0, f32m);
    }

    const long base = (long)gidx * (32 * RT);

#pragma unroll
    for (int tt = 0; tt < RT; ++tt) {
        const long row0 = base + tt * 32 + rtile * 16;
        if (row0 >= n_rows) break;               // wave-uniform
        const long row = row0 + m;               // this lane's output row

        // x fragment (B operand; index lane&15 = m = x-row)
        bf16x8 afrag[4];
        {
            long arow = row < n_rows ? row : n_rows - 1;   // clamp; stores guarded
            if (!f32m) {
#pragma unroll
                for (int ks = 0; ks < 4; ++ks)
                    afrag[ks] = *(const bf16x8*)(x + arow * HID + ks * 32 + quad * 8);
            } else {
                const float* xf = (const float*)x;
#pragma unroll
                for (int ks = 0; ks < 4; ++ks)
#pragma unroll
                    for (int j = 0; j < 8; ++j)
                        afrag[ks][j] = (short)f2b(xf[arow * HID + ks * 32 + quad * 8 + j]);
            }
        }

        f32x4 acc[4];
#pragma unroll
        for (int nt = 0; nt < 4; ++nt) acc[nt] = (f32x4){0.f, 0.f, 0.f, 0.f};
#pragma unroll
        for (int nt = 0; nt < 4; ++nt)
#pragma unroll
            for (int ks = 0; ks < 4; ++ks)
                acc[nt] = __builtin_amdgcn_mfma_f32_16x16x32_bf16(
                    wfrag[ks][nt], afrag[ks], acc[nt], 0, 0, 0);
        // acc[nt][r] = out[row][nhalf*64 + nt*16 + quad*4 + r]

        float als_p[2] = {0.f, 0.f}, ald_p[2] = {0.f, 0.f};
#pragma unroll
        for (int nt = 0; nt < 4; ++nt) {
            const int c0 = nhalf * 64 + nt * 16 + quad * 4;
            float v0 = acc[nt][0] + bb[nt][0];
            float v1 = acc[nt][1] + bb[nt][1];
            float v2 = acc[nt][2] + bb[nt][2];
            float v3 = acc[nt][3] + bb[nt][3];
            if (row < n_rows) {
                u16x4 st = {f2b(v0), f2b(v1), f2b(v2), f2b(v3)};
                *(u16x4*)(hp + row * HID + c0) = st;
            }
            const int hl = nt >> 1;
            als_p[hl] += v0 * as4[nt][0] + v1 * as4[nt][1] + v2 * as4[nt][2] + v3 * as4[nt][3];
            ald_p[hl] += v0 * ad4[nt][0] + v1 * ad4[nt][1] + v2 * ad4[nt][2] + v3 * ad4[nt][3];
        }
        // reduce over the 4 quad-lanes (lane bits 4..5)
#pragma unroll
        for (int off = 16; off < 64; off <<= 1) {
            als_p[0] += __shfl_xor(als_p[0], off);
            als_p[1] += __shfl_xor(als_p[1], off);
            ald_p[0] += __shfl_xor(ald_p[0], off);
            ald_p[1] += __shfl_xor(ald_p[1], off);
        }
        if (quad == 0 && row < n_rows) {
            const int hb = nhalf * 2;   // hb in {0,2}: 8B-aligned pair stores
            *(f32x2*)(al_s + row * 4 + hb) = (f32x2){als_p[0], als_p[1]};
            *(f32x2*)(al_d + row * 4 + hb) = (f32x2){ald_p[0], ald_p[1]};
        }
    }
}

// ---------------------------------------------------------------------------
// Per-dst layer-1 aggregate on ELL + epilogue. 16 lanes per dst, u16x8 hp
// loads, native __expf, al2s packed into hp2.w.
// Round-14: WEIGHT DEDUP — previously all 4 lanes of a quad (same h)
// gathered all four al_s values and computed all four exps (4x redundant).
// Now lane k=lt&3 gathers only its slot's al_s and computes one weight;
// the quad exchanges via 4 __shfl (quad lanes share a dst -> same niter ->
// shuffle sources always active). Masking now clamps the SLOT index to
// end-1 (garbage loads duplicate the last valid edge, L1-hot) instead of
// clamping src to row 0 — removes 8 compare+selects per iter.
// ---------------------------------------------------------------------------
__global__ __launch_bounds__(256) void msg1_fused_k(
    const int* __restrict__ degc,
    const int* __restrict__ csrc,
    const unsigned short* __restrict__ hp,
    const float* __restrict__ al_s, const float* __restrict__ al_d,
    const unsigned short* __restrict__ bn_w, const unsigned short* __restrict__ bn_b,
    const unsigned short* __restrict__ bn_m, const unsigned short* __restrict__ bn_v,
    const unsigned short* __restrict__ w2,   const unsigned short* __restrict__ b2,
    const unsigned short* __restrict__ a2s,  const unsigned short* __restrict__ a2d,
    const unsigned short* __restrict__ xp,
    float* __restrict__ hp2, float* __restrict__ al2d,
    int n_p)
{
    const bool f32m = detect_f32(xp);
    __shared__ float s_inv[128], s_mu[128], s_beta[128];
    __shared__ float s_w2[3][128];
    __shared__ float s_scal[9];    // b2[0:3], a2s[0:3], a2d[0:3]
    {
        int t = threadIdx.x;
        if (t < 128) {
            float bw = ldf(bn_w, t, f32m), bv = ldf(bn_v, t, f32m);
            s_inv[t]  = bw / sqrtf(bv + 1e-5f);
            s_mu[t]   = ldf(bn_m, t, f32m);
            s_beta[t] = ldf(bn_b, t, f32m);
            s_w2[0][t] = ldf(w2, 0 * HID + t, f32m);
            s_w2[1][t] = ldf(w2, 1 * HID + t, f32m);
            s_w2[2][t] = ldf(w2, 2 * HID + t, f32m);
        } else if (t < 131) {
            int k = t - 128;
            s_scal[k]     = ldf(b2, k, f32m);
            s_scal[3 + k] = ldf(a2s, k, f32m);
            s_scal[6 + k] = ldf(a2d, k, f32m);
        }
    }
    __syncthreads();

    const int lane = threadIdx.x & 63;
    const int lt = lane & 15;
    const int d  = blockIdx.x * 16 + (threadIdx.x >> 4);
    if (d >= n_p) return;
    const int h  = lt >> 2;       // lane covers cols lt*8..lt*8+7 (head h)
    const int k  = lt & 3;        // this lane's slot within the 4-edge group
    const int qb = lane & ~3;     // absolute quad base within the wave
    const float ald = al_d[(long)d * 4 + h];
    const int deg = degc[d];
    const int beg = d << 5, end = beg + deg;
    const int niter = (deg + 3) >> 2;
    const int elast = end - 1;    // only used when niter > 0

    float dsum = 0.f;
    float acc[8] = {0.f,0.f,0.f,0.f,0.f,0.f,0.f,0.f};
    int p = beg;
    for (int it = 0; it < niter; ++it, p += 4) {
        int p0 = p + 0 > elast ? elast : p + 0;
        int p1 = p + 1 > elast ? elast : p + 1;
        int p2 = p + 2 > elast ? elast : p + 2;
        int p3 = p + 3 > elast ? elast : p + 3;
        int s0 = csrc[p0], s1 = csrc[p1], s2 = csrc[p2], s3 = csrc[p3];
        int pk = p + k > elast ? elast : p + k;
        int sk = csrc[pk];
        float a = al_s[(long)sk * 4 + h];      // ONE gather per lane (was 4)
        u16x8 v0 = *(const u16x8*)(hp + (long)s0 * HID + lt * 8);
        u16x8 v1 = *(const u16x8*)(hp + (long)s1 * HID + lt * 8);
        u16x8 v2 = *(const u16x8*)(hp + (long)s2 * HID + lt * 8);
        u16x8 v3 = *(const u16x8*)(hp + (long)s3 * HID + lt * 8);
        float wk = (p + k < end) ? __expf(lrelu(a + ald)) : 0.f;  // ONE exp
        float w0 = __shfl(wk, qb + 0);
        float w1 = __shfl(wk, qb + 1);
        float w2_ = __shfl(wk, qb + 2);
        float w3 = __shfl(wk, qb + 3);
        dsum += (w0 + w1) + (w2_ + w3);
#pragma unroll
        for (int kk = 0; kk < 8; ++kk)
            acc[kk] += b2f(v0[kk]) * w0 + b2f(v1[kk]) * w1
                     + b2f(v2[kk]) * w2_ + b2f(v3[kk]) * w3;
    }

    // ---- epilogue from LDS ----
    const float r = 1.f / (dsum + 1e-16f);
    float p0 = 0.f, p1 = 0.f, p2 = 0.f;
#pragma unroll
    for (int kk = 0; kk < 8; ++kk) {
        int j = lt * 8 + kk;
        float v = acc[kk] * r;
        v = v > 0.f ? v : 0.f;                            // relu
        v = (v - s_mu[j]) * s_inv[j] + s_beta[j];         // BN eval (folded)
        v = v > 0.f ? v : (__expf(v) - 1.f);              // ELU
        p0 += v * s_w2[0][j];
        p1 += v * s_w2[1][j];
        p2 += v * s_w2[2][j];
    }
#pragma unroll
    for (int msk = 8; msk; msk >>= 1) {
        p0 += __shfl_xor(p0, msk);
        p1 += __shfl_xor(p1, msk);
        p2 += __shfl_xor(p2, msk);
    }
    if (lt == 0) {
        p0 += s_scal[0]; p1 += s_scal[1]; p2 += s_scal[2];
        float a2sv = p0 * s_scal[3] + p1 * s_scal[4] + p2 * s_scal[5];
        *(f32x4*)(hp2 + (long)d * 4) = (f32x4){p0, p1, p2, a2sv};  // al2s in .w
        al2d[d] = p0 * s_scal[6] + p1 * s_scal[7] + p2 * s_scal[8];
    }
}

// ---------------------------------------------------------------------------
// Layer-2 attention + relu + log_softmax on ELL. 4 lanes per dst; ONE f32x4
// gather per edge (features + packed al2s).
// ---------------------------------------------------------------------------
__global__ __launch_bounds__(256) void l2final_k(
    const int* __restrict__ degc,
    const int* __restrict__ csrc,
    const float* __restrict__ hp2,
    const float* __restrict__ al2d,
    const unsigned short* __restrict__ xp,
    void* __restrict__ out, int n_p)
{
    const bool f32m = detect_f32(xp);
    const int t  = blockIdx.x * 256 + threadIdx.x;
    const int d  = t >> 2;
    const int sl = t & 3;
    if (d >= n_p) return;
    const int beg = d << 5, end = beg + degc[d];
    const float ald = al2d[d];

    float a0s = 0.f, a1s = 0.f, a2s_ = 0.f, ds = 0.f;
    for (int p = beg + sl; p < end; p += 4) {
        int s = csrc[p];
        f32x4 hv = *(const f32x4*)(hp2 + (long)s * 4);
        float w = __expf(lrelu(hv[3] + ald));
        ds += w;
        a0s += hv[0] * w; a1s += hv[1] * w; a2s_ += hv[2] * w;
    }
    // quad reduce (lanes of one dst are 4 consecutive lanes)
#pragma unroll
    for (int off = 1; off < 4; off <<= 1) {
        ds  += __shfl_xor(ds, off);
        a0s += __shfl_xor(a0s, off);
        a1s += __shfl_xor(a1s, off);
        a2s_ += __shfl_xor(a2s_, off);
    }
    if (sl != 0) return;

    const float r = 1.f / (ds + 1e-16f);
    float v0 = fmaxf(a0s * r, 0.f);
    float v1 = fmaxf(a1s * r, 0.f);
    float v2 = fmaxf(a2s_ * r, 0.f);
    float m = fmaxf(v0, fmaxf(v1, v2));
    float lse = m + __logf(__expf(v0 - m) + __expf(v1 - m) + __expf(v2 - m));
    if (f32m) {
        float* o = (float*)out;
        o[(long)d * 3 + 0] = v0 - lse;
        o[(long)d * 3 + 1] = v1 - lse;
        o[(long)d * 3 + 2] = v2 - lse;
    } else {
        __hip_bfloat16* o = (__hip_bfloat16*)out;
        o[(long)d * 3 + 0] = __float2bfloat16(v0 - lse);
        o[(long)d * 3 + 1] = __float2bfloat16(v1 - lse);
        o[(long)d * 3 + 2] = __float2bfloat16(v2 - lse);
    }
}

extern "C" void kernel_launch(void* const* d_in, const int* in_sizes, int n_in,
                              void* d_out, int out_size, void* d_ws, size_t ws_size,
                              hipStream_t stream)
{
    const unsigned short* x_p = (const unsigned short*)d_in[0];
    const int*            ei  = (const int*)d_in[5];             // ei_sim [2,E]
    const unsigned short* w1p = (const unsigned short*)d_in[6];
    const unsigned short* b1p = (const unsigned short*)d_in[7];
    const unsigned short* a1s = (const unsigned short*)d_in[16]; // a1_src_sim
    const unsigned short* a1d = (const unsigned short*)d_in[17]; // a1_dst_sim
    const unsigned short* bnw = (const unsigned short*)d_in[18];
    const unsigned short* bnb = (const unsigned short*)d_in[19];
    const unsigned short* bnm = (const unsigned short*)d_in[20];
    const unsigned short* bnv = (const unsigned short*)d_in[21];
    const unsigned short* w2p = (const unsigned short*)d_in[22];
    const unsigned short* b2p = (const unsigned short*)d_in[23];
    const unsigned short* a2s = (const unsigned short*)d_in[32]; // a2_src_sim
    const unsigned short* a2d = (const unsigned short*)d_in[33]; // a2_dst_sim

    const int n_p   = in_sizes[0] / HID;  // 100000
    const int e_sim = in_sizes[5] / 2;    // 400000

    float* ws = (float*)d_ws;
    size_t o = 0;
    // ---- zero-init region: cursor (doubles as degree after scatter) ----
    int* cursor = (int*)(ws + o);                     o += (size_t)n_p;
    size_t zlen = o;
    // ---- rest (fully written before read) ----
    int* csrc   = (int*)(ws + o);                     o += (size_t)n_p * ELLW;   // ELL
    unsigned short* hp = (unsigned short*)(ws + o);   o += (size_t)n_p * HID / 2; // bf16
    float* al_s = ws + o;                             o += (size_t)n_p * 4;
    float* al_d = ws + o;                             o += (size_t)n_p * 4;
    float* hp2  = ws + o;                             o += (size_t)n_p * 4;      // .w = al2s
    float* al2d = ws + o;                             o += (size_t)n_p;

    hipMemsetAsync((void*)ws, 0, zlen * sizeof(float), stream);

    // Fused gemm1 + ELL scatter, R10 geometry (every 3rd block = scatter)
    const int gb = (n_p + 32 * RT - 1) / (32 * RT);      // 782
    const int sb = (e_sim + 4 * 256 - 1) / (4 * 256);    // 391
    gemm1_scat_k<<<gb + sb, 256, 0, stream>>>(
        x_p, w1p, b1p, a1s, a1d, hp, al_s, al_d, n_p, ei, e_sim, cursor, csrc, gb, sb);

    // Layer-1 aggregate + epilogue (ELL: rowptr implicit, deg = cursor)
    msg1_fused_k<<<(n_p + 15) / 16, 256, 0, stream>>>(cursor, csrc, hp, al_s, al_d,
                                                      bnw, bnb, bnm, bnv, w2p, b2p,
                                                      a2s, a2d, x_p,
                                                      hp2, al2d, n_p);

    // Layer 2 attention + relu + log_softmax (4 lanes per dst, packed gather)
    l2final_k<<<((long)n_p * 4 + 255) / 256, 256, 0, stream>>>(
        cursor, csrc, hp2, al2d, x_p, d_out, n_p);
}

// Round 15
// 233.461 us; speedup vs baseline: 1.0227x; 1.0227x over previous
//
#include <hip/hip_runtime.h>
#include <hip/hip_bf16.h>

typedef float f32x4 __attribute__((ext_vector_type(4)));
typedef float f32x2 __attribute__((ext_vector_type(2)));
typedef unsigned short u16x4 __attribute__((ext_vector_type(4)));
typedef unsigned short u16x8 __attribute__((ext_vector_type(8)));
typedef short bf16x8 __attribute__((ext_vector_type(8)));

#define HID 128
#define RT  4    // 32-row steps per gemm block (block covers 128 rows)
#define ELLW 32  // ELL slot width: max degree ~17 on Poisson(4) input, 32 is safe

__device__ __forceinline__ float b2f(unsigned short u) {
    return __uint_as_float(((unsigned int)u) << 16);
}
__device__ __forceinline__ unsigned short f2b(float f) {
    unsigned int u = __float_as_uint(f);
    unsigned int r = (u + 0x7FFFu + ((u >> 16) & 1u)) >> 16;   // RNE
    return (unsigned short)r;
}

// --- runtime dtype probes (uniform across all threads; deterministic) -------
__device__ __forceinline__ bool detect_f32(const unsigned short* xp) {
    int sane = 0;
#pragma unroll
    for (int i = 0; i < 16; ++i) {
        int ex = (xp[2 * i] >> 7) & 0xFF;
        sane += (ex >= 120 && ex <= 130);
    }
    return sane < 8;   // true => float inputs are fp32
}
__device__ __forceinline__ bool detect_i64(const int* ei) {
    return (ei[1] | ei[3] | ei[5] | ei[7]) == 0;
}
__device__ __forceinline__ float ldf(const unsigned short* p, long i, bool f32) {
    return f32 ? ((const float*)p)[i] : b2f(p[i]);
}
// 4 contiguous floats at index c0, from bf16 or f32 storage
__device__ __forceinline__ f32x4 ld4(const unsigned short* p, int c0, bool f32) {
    if (f32) return *(const f32x4*)((const float*)p + c0);
    u16x4 q = *(const u16x4*)(p + c0);
    return (f32x4){b2f(q[0]), b2f(q[1]), b2f(q[2]), b2f(q[3])};
}
__device__ __forceinline__ int ei_at(const int* ei, long idx, bool i64) {
    return i64 ? ei[2 * idx] : ei[idx];
}
__device__ __forceinline__ float lrelu(float a) {
    return a > 0.f ? a : 0.2f * a;
}

// ---------------------------------------------------------------------------
// FUSED with INTERLEAVED roles, R10/R12/R13-proven form: every 3rd block
// (bid%3==2) runs the ELL scatter (4 strided edges/thread, phase-split
// atomics-then-stores); the rest run gemm1 (R4 body + R12 param hoist +
// R13 packed f32x2 al stores — fused dispatch measured 59-62us).
// DO NOT change geometry: 1:1/half-size scatter blocks regressed (R11);
// appended blocks serialize (R7/R8).
// ---------------------------------------------------------------------------
__global__ __launch_bounds__(256) void gemm1_scat_k(
    const unsigned short* __restrict__ x,
    const unsigned short* __restrict__ w,
    const unsigned short* __restrict__ bias,
    const unsigned short* __restrict__ a1s,
    const unsigned short* __restrict__ a1d,
    unsigned short* __restrict__ hp,
    float* __restrict__ al_s, float* __restrict__ al_d, int n_rows,
    const int* __restrict__ ei, int E,
    int* __restrict__ cursor, int* __restrict__ csrc, int gb, int sb)
{
    const int bid = (int)blockIdx.x;
    const int sb3 = 3 * sb;
    if (bid < sb3 && (bid % 3) == 2) {
        // ---- ELL scatter: 4 independent strided edges, phase-split ----
        const bool i64 = detect_i64(ei);
        const int nth = sb * 256;
        const int idx = (bid / 3) * 256 + (int)threadIdx.x;
        int s[4], d[4], pos[4]; bool v[4];
#pragma unroll
        for (int k = 0; k < 4; ++k) {
            int e = idx + k * nth;
            v[k] = e < E;
            if (v[k]) {
                s[k] = ei_at(ei, e, i64);
                d[k] = ei_at(ei, (long)E + e, i64);
            }
        }
#pragma unroll
        for (int k = 0; k < 4; ++k)
            if (v[k]) pos[k] = atomicAdd(&cursor[d[k]], 1);
#pragma unroll
        for (int k = 0; k < 4; ++k)
            if (v[k]) csrc[(d[k] << 5) + pos[k]] = s[k];
        return;
    }
    const int gidx = (bid < sb3) ? (bid - (bid + 1) / 3) : (bid - sb);
    if (gidx >= gb) return;

    // ---- gemm phase (proven form; params hoisted out of tt loop) ----
    const bool f32m = detect_f32(x);
    const int wave  = threadIdx.x >> 6;
    const int lane  = threadIdx.x & 63;
    const int nhalf = wave & 1;   // which 64-col half
    const int rtile = wave >> 1;  // which 16-row subtile
    const int m     = lane & 15;
    const int quad  = lane >> 4;

    // W fragments: loaded once, reused across all RT tiles (A operand)
    bf16x8 wfrag[4][4];
#pragma unroll
    for (int ks = 0; ks < 4; ++ks)
#pragma unroll
        for (int nt = 0; nt < 4; ++nt) {
            int col = nhalf * 64 + nt * 16 + m;
            if (!f32m) {
                wfrag[ks][nt] = *(const bf16x8*)(w + (long)col * HID + ks * 32 + quad * 8);
            } else {
                const float* wf = (const float*)w;
#pragma unroll
                for (int j = 0; j < 8; ++j)
                    wfrag[ks][nt][j] = (short)f2b(wf[(long)col * HID + ks * 32 + quad * 8 + j]);
            }
        }

    // bias/attention params: tt-invariant — hoisted
    f32x4 bb[4], as4[4], ad4[4];
#pragma unroll
    for (int nt = 0; nt < 4; ++nt) {
        const int c0 = nhalf * 64 + nt * 16 + quad * 4;
        bb[nt]  = ld4(bias, c0, f32m);
        as4[nt] = ld4(a1s,  c0, f32m);
        ad4[nt] = ld4(a1d,  c0, f32m);
    }

    const long base = (long)gidx * (32 * RT);

#pragma unroll
    for (int tt = 0; tt < RT; ++tt) {
        const long row0 = base + tt * 32 + rtile * 16;
        if (row0 >= n_rows) break;               // wave-uniform
        const long row = row0 + m;               // this lane's output row

        // x fragment (B operand; index lane&15 = m = x-row)
        bf16x8 afrag[4];
        {
            long arow = row < n_rows ? row : n_rows - 1;   // clamp; stores guarded
            if (!f32m) {
#pragma unroll
                for (int ks = 0; ks < 4; ++ks)
                    afrag[ks] = *(const bf16x8*)(x + arow * HID + ks * 32 + quad * 8);
            } else {
                const float* xf = (const float*)x;
#pragma unroll
                for (int ks = 0; ks < 4; ++ks)
#pragma unroll
                    for (int j = 0; j < 8; ++j)
                        afrag[ks][j] = (short)f2b(xf[arow * HID + ks * 32 + quad * 8 + j]);
            }
        }

        f32x4 acc[4];
#pragma unroll
        for (int nt = 0; nt < 4; ++nt) acc[nt] = (f32x4){0.f, 0.f, 0.f, 0.f};
#pragma unroll
        for (int nt = 0; nt < 4; ++nt)
#pragma unroll
            for (int ks = 0; ks < 4; ++ks)
                acc[nt] = __builtin_amdgcn_mfma_f32_16x16x32_bf16(
                    wfrag[ks][nt], afrag[ks], acc[nt], 0, 0, 0);
        // acc[nt][r] = out[row][nhalf*64 + nt*16 + quad*4 + r]

        float als_p[2] = {0.f, 0.f}, ald_p[2] = {0.f, 0.f};
#pragma unroll
        for (int nt = 0; nt < 4; ++nt) {
            const int c0 = nhalf * 64 + nt * 16 + quad * 4;
            float v0 = acc[nt][0] + bb[nt][0];
            float v1 = acc[nt][1] + bb[nt][1];
            float v2 = acc[nt][2] + bb[nt][2];
            float v3 = acc[nt][3] + bb[nt][3];
            if (row < n_rows) {
                u16x4 st = {f2b(v0), f2b(v1), f2b(v2), f2b(v3)};
                *(u16x4*)(hp + row * HID + c0) = st;
            }
            const int hl = nt >> 1;
            als_p[hl] += v0 * as4[nt][0] + v1 * as4[nt][1] + v2 * as4[nt][2] + v3 * as4[nt][3];
            ald_p[hl] += v0 * ad4[nt][0] + v1 * ad4[nt][1] + v2 * ad4[nt][2] + v3 * ad4[nt][3];
        }
        // reduce over the 4 quad-lanes (lane bits 4..5)
#pragma unroll
        for (int off = 16; off < 64; off <<= 1) {
            als_p[0] += __shfl_xor(als_p[0], off);
            als_p[1] += __shfl_xor(als_p[1], off);
            ald_p[0] += __shfl_xor(ald_p[0], off);
            ald_p[1] += __shfl_xor(ald_p[1], off);
        }
        if (quad == 0 && row < n_rows) {
            const int hb = nhalf * 2;   // hb in {0,2}: 8B-aligned pair stores
            *(f32x2*)(al_s + row * 4 + hb) = (f32x2){als_p[0], als_p[1]};
            *(f32x2*)(al_d + row * 4 + hb) = (f32x2){ald_p[0], ald_p[1]};
        }
    }
}

// ---------------------------------------------------------------------------
// Per-dst layer-1 aggregate on ELL + epilogue. 16 lanes per dst, u16x8 hp
// loads, native __expf, al2s packed into hp2.w. R13-proven form (best
// total 233.98): masked uniform loop, ceil(deg/4) 4-wide iterations,
// garbage srcs clamped to row 0, weights masked to 0.
// R14 lesson: quad shfl weight-dedup REGRESSED (+4.8us) — the shfls put a
// serial DS dependency in a loop whose gathers were parallel and cheap.
// Do not re-attempt cross-lane exchange inside this loop.
// ---------------------------------------------------------------------------
__global__ __launch_bounds__(256) void msg1_fused_k(
    const int* __restrict__ degc,
    const int* __restrict__ csrc,
    const unsigned short* __restrict__ hp,
    const float* __restrict__ al_s, const float* __restrict__ al_d,
    const unsigned short* __restrict__ bn_w, const unsigned short* __restrict__ bn_b,
    const unsigned short* __restrict__ bn_m, const unsigned short* __restrict__ bn_v,
    const unsigned short* __restrict__ w2,   const unsigned short* __restrict__ b2,
    const unsigned short* __restrict__ a2s,  const unsigned short* __restrict__ a2d,
    const unsigned short* __restrict__ xp,
    float* __restrict__ hp2, float* __restrict__ al2d,
    int n_p)
{
    const bool f32m = detect_f32(xp);
    __shared__ float s_inv[128], s_mu[128], s_beta[128];
    __shared__ float s_w2[3][128];
    __shared__ float s_scal[9];    // b2[0:3], a2s[0:3], a2d[0:3]
    {
        int t = threadIdx.x;
        if (t < 128) {
            float bw = ldf(bn_w, t, f32m), bv = ldf(bn_v, t, f32m);
            s_inv[t]  = bw / sqrtf(bv + 1e-5f);
            s_mu[t]   = ldf(bn_m, t, f32m);
            s_beta[t] = ldf(bn_b, t, f32m);
            s_w2[0][t] = ldf(w2, 0 * HID + t, f32m);
            s_w2[1][t] = ldf(w2, 1 * HID + t, f32m);
            s_w2[2][t] = ldf(w2, 2 * HID + t, f32m);
        } else if (t < 131) {
            int k = t - 128;
            s_scal[k]     = ldf(b2, k, f32m);
            s_scal[3 + k] = ldf(a2s, k, f32m);
            s_scal[6 + k] = ldf(a2d, k, f32m);
        }
    }
    __syncthreads();

    const int lt = threadIdx.x & 15;
    const int d  = blockIdx.x * 16 + (threadIdx.x >> 4);
    if (d >= n_p) return;
    const int h = lt >> 2;                       // lane covers cols lt*8..lt*8+7
    const float ald = al_d[(long)d * 4 + h];
    const int deg = degc[d];
    const int beg = d << 5, end = beg + deg;
    const int niter = (deg + 3) >> 2;

    float dsum = 0.f;
    float acc[8] = {0.f,0.f,0.f,0.f,0.f,0.f,0.f,0.f};
    int p = beg;
    for (int it = 0; it < niter; ++it, p += 4) {
        int s0 = csrc[p + 0], s1 = csrc[p + 1], s2 = csrc[p + 2], s3 = csrc[p + 3];
        // clamp garbage (unwritten ELL slots) to valid row 0
        unsigned u0 = (unsigned)s0 < (unsigned)n_p ? (unsigned)s0 : 0u;
        unsigned u1 = (unsigned)s1 < (unsigned)n_p ? (unsigned)s1 : 0u;
        unsigned u2 = (unsigned)s2 < (unsigned)n_p ? (unsigned)s2 : 0u;
        unsigned u3 = (unsigned)s3 < (unsigned)n_p ? (unsigned)s3 : 0u;
        float a0 = al_s[(long)u0 * 4 + h];
        float a1 = al_s[(long)u1 * 4 + h];
        float a2 = al_s[(long)u2 * 4 + h];
        float a3 = al_s[(long)u3 * 4 + h];
        u16x8 v0 = *(const u16x8*)(hp + (long)u0 * HID + lt * 8);
        u16x8 v1 = *(const u16x8*)(hp + (long)u1 * HID + lt * 8);
        u16x8 v2 = *(const u16x8*)(hp + (long)u2 * HID + lt * 8);
        u16x8 v3 = *(const u16x8*)(hp + (long)u3 * HID + lt * 8);
        float w0 = (p + 0 < end) ? __expf(lrelu(a0 + ald)) : 0.f;
        float w1 = (p + 1 < end) ? __expf(lrelu(a1 + ald)) : 0.f;
        float w2_ = (p + 2 < end) ? __expf(lrelu(a2 + ald)) : 0.f;
        float w3 = (p + 3 < end) ? __expf(lrelu(a3 + ald)) : 0.f;
        dsum += (w0 + w1) + (w2_ + w3);
#pragma unroll
        for (int k = 0; k < 8; ++k)
            acc[k] += b2f(v0[k]) * w0 + b2f(v1[k]) * w1
                    + b2f(v2[k]) * w2_ + b2f(v3[k]) * w3;
    }

    // ---- epilogue from LDS ----
    const float r = 1.f / (dsum + 1e-16f);
    float p0 = 0.f, p1 = 0.f, p2 = 0.f;
#pragma unroll
    for (int k = 0; k < 8; ++k) {
        int j = lt * 8 + k;
        float v = acc[k] * r;
        v = v > 0.f ? v : 0.f;                            // relu
        v = (v - s_mu[j]) * s_inv[j] + s_beta[j];         // BN eval (folded)
        v = v > 0.f ? v : (__expf(v) - 1.f);              // ELU
        p0 += v * s_w2[0][j];
        p1 += v * s_w2[1][j];
        p2 += v * s_w2[2][j];
    }
#pragma unroll
    for (int msk = 8; msk; msk >>= 1) {
        p0 += __shfl_xor(p0, msk);
        p1 += __shfl_xor(p1, msk);
        p2 += __shfl_xor(p2, msk);
    }
    if (lt == 0) {
        p0 += s_scal[0]; p1 += s_scal[1]; p2 += s_scal[2];
        float a2sv = p0 * s_scal[3] + p1 * s_scal[4] + p2 * s_scal[5];
        *(f32x4*)(hp2 + (long)d * 4) = (f32x4){p0, p1, p2, a2sv};  // al2s in .w
        al2d[d] = p0 * s_scal[6] + p1 * s_scal[7] + p2 * s_scal[8];
    }
}

// ---------------------------------------------------------------------------
// Layer-2 attention + relu + log_softmax on ELL. 4 lanes per dst; ONE f32x4
// gather per edge (features + packed al2s).
// ---------------------------------------------------------------------------
__global__ __launch_bounds__(256) void l2final_k(
    const int* __restrict__ degc,
    const int* __restrict__ csrc,
    const float* __restrict__ hp2,
    const float* __restrict__ al2d,
    const unsigned short* __restrict__ xp,
    void* __restrict__ out, int n_p)
{
    const bool f32m = detect_f32(xp);
    const int t  = blockIdx.x * 256 + threadIdx.x;
    const int d  = t >> 2;
    const int sl = t & 3;
    if (d >= n_p) return;
    const int beg = d << 5, end = beg + degc[d];
    const float ald = al2d[d];

    float a0s = 0.f, a1s = 0.f, a2s_ = 0.f, ds = 0.f;
    for (int p = beg + sl; p < end; p += 4) {
        int s = csrc[p];
        f32x4 hv = *(const f32x4*)(hp2 + (long)s * 4);
        float w = __expf(lrelu(hv[3] + ald));
        ds += w;
        a0s += hv[0] * w; a1s += hv[1] * w; a2s_ += hv[2] * w;
    }
    // quad reduce (lanes of one dst are 4 consecutive lanes)
#pragma unroll
    for (int off = 1; off < 4; off <<= 1) {
        ds  += __shfl_xor(ds, off);
        a0s += __shfl_xor(a0s, off);
        a1s += __shfl_xor(a1s, off);
        a2s_ += __shfl_xor(a2s_, off);
    }
    if (sl != 0) return;

    const float r = 1.f / (ds + 1e-16f);
    float v0 = fmaxf(a0s * r, 0.f);
    float v1 = fmaxf(a1s * r, 0.f);
    float v2 = fmaxf(a2s_ * r, 0.f);
    float m = fmaxf(v0, fmaxf(v1, v2));
    float lse = m + __logf(__expf(v0 - m) + __expf(v1 - m) + __expf(v2 - m));
    if (f32m) {
        float* o = (float*)out;
        o[(long)d * 3 + 0] = v0 - lse;
        o[(long)d * 3 + 1] = v1 - lse;
        o[(long)d * 3 + 2] = v2 - lse;
    } else {
        __hip_bfloat16* o = (__hip_bfloat16*)out;
        o[(long)d * 3 + 0] = __float2bfloat16(v0 - lse);
        o[(long)d * 3 + 1] = __float2bfloat16(v1 - lse);
        o[(long)d * 3 + 2] = __float2bfloat16(v2 - lse);
    }
}

extern "C" void kernel_launch(void* const* d_in, const int* in_sizes, int n_in,
                              void* d_out, int out_size, void* d_ws, size_t ws_size,
                              hipStream_t stream)
{
    const unsigned short* x_p = (const unsigned short*)d_in[0];
    const int*            ei  = (const int*)d_in[5];             // ei_sim [2,E]
    const unsigned short* w1p = (const unsigned short*)d_in[6];
    const unsigned short* b1p = (const unsigned short*)d_in[7];
    const unsigned short* a1s = (const unsigned short*)d_in[16]; // a1_src_sim
    const unsigned short* a1d = (const unsigned short*)d_in[17]; // a1_dst_sim
    const unsigned short* bnw = (const unsigned short*)d_in[18];
    const unsigned short* bnb = (const unsigned short*)d_in[19];
    const unsigned short* bnm = (const unsigned short*)d_in[20];
    const unsigned short* bnv = (const unsigned short*)d_in[21];
    const unsigned short* w2p = (const unsigned short*)d_in[22];
    const unsigned short* b2p = (const unsigned short*)d_in[23];
    const unsigned short* a2s = (const unsigned short*)d_in[32]; // a2_src_sim
    const unsigned short* a2d = (const unsigned short*)d_in[33]; // a2_dst_sim

    const int n_p   = in_sizes[0] / HID;  // 100000
    const int e_sim = in_sizes[5] / 2;    // 400000

    float* ws = (float*)d_ws;
    size_t o = 0;
    // ---- zero-init region: cursor (doubles as degree after scatter) ----
    int* cursor = (int*)(ws + o);                     o += (size_t)n_p;
    size_t zlen = o;
    // ---- rest (fully written before read) ----
    int* csrc   = (int*)(ws + o);                     o += (size_t)n_p * ELLW;   // ELL
    unsigned short* hp = (unsigned short*)(ws + o);   o += (size_t)n_p * HID / 2; // bf16
    float* al_s = ws + o;                             o += (size_t)n_p * 4;
    float* al_d = ws + o;                             o += (size_t)n_p * 4;
    float* hp2  = ws + o;                             o += (size_t)n_p * 4;      // .w = al2s
    float* al2d = ws + o;                             o += (size_t)n_p;

    hipMemsetAsync((void*)ws, 0, zlen * sizeof(float), stream);

    // Fused gemm1 + ELL scatter, R10 geometry (every 3rd block = scatter)
    const int gb = (n_p + 32 * RT - 1) / (32 * RT);      // 782
    const int sb = (e_sim + 4 * 256 - 1) / (4 * 256);    // 391
    gemm1_scat_k<<<gb + sb, 256, 0, stream>>>(
        x_p, w1p, b1p, a1s, a1d, hp, al_s, al_d, n_p, ei, e_sim, cursor, csrc, gb, sb);

    // Layer-1 aggregate + epilogue (ELL: rowptr implicit, deg = cursor)
    msg1_fused_k<<<(n_p + 15) / 16, 256, 0, stream>>>(cursor, csrc, hp, al_s, al_d,
                                                      bnw, bnb, bnm, bnv, w2p, b2p,
                                                      a2s, a2d, x_p,
                                                      hp2, al2d, n_p);

    // Layer 2 attention + relu + log_softmax (4 lanes per dst, packed gather)
    l2final_k<<<((long)n_p * 4 + 255) / 256, 256, 0, stream>>>(
        cursor, csrc, hp2, al2d, x_p, d_out, n_p);
}